// Round 1
// baseline (416.115 us; speedup 1.0000x reference)
//
#include <hip/hip_runtime.h>
#include <stdint.h>
#include <math.h>

#define N_ROWS 2048
#define M_CAND 131072
#define DIMK 128
#define DOUT 10
#define NCHUNK 128        // column chunks in main GEMM (each = 8 tiles of 128 cands)
#define CHUNK_ITERS 8
#define LOG2E 1.4426950408889634f

typedef __attribute__((ext_vector_type(8))) __bf16 bf16x8;   // MFMA A/B frag (4 VGPRs)
typedef __attribute__((ext_vector_type(8))) short s16x8;     // raw bf16 storage vec
typedef __attribute__((ext_vector_type(4))) float f32x4;     // MFMA C/D frag
typedef __attribute__((address_space(3))) void lds_void;
typedef const __attribute__((address_space(1))) void gbl_void;

__device__ __forceinline__ short f2bf(float f) {   // RNE fp32->bf16
  union { float f; unsigned u; } v; v.f = f;
  return (short)((v.u + 0x7fffu + ((v.u >> 16) & 1u)) >> 16);
}
__device__ __forceinline__ float bf2f(short h) {
  union { unsigned u; float f; } v;
  v.u = ((unsigned)(unsigned short)h) << 16; return v.f;
}
__device__ __forceinline__ float fast_sqrtf(float x) {
#if __has_builtin(__builtin_amdgcn_sqrtf)
  return __builtin_amdgcn_sqrtf(x);
#else
  return sqrtf(x);
#endif
}
__device__ __forceinline__ float fast_exp2f(float x) {
#if __has_builtin(__builtin_amdgcn_exp2f)
  return __builtin_amdgcn_exp2f(x);
#else
  return exp2f(x);
#endif
}

// Swizzled 128x128 bf16 tile: LDS slot (r,s) [16B granules] holds global granule g = s^(r&15).
// Staged direct-to-LDS; swizzle applied on the global source address (free).
__device__ __forceinline__ void stage_tile_async(const short* gbase, short* lds, int t) {
  int w = t >> 6;
#pragma unroll
  for (int i = 0; i < 8; ++i) {
    int flat = i * 256 + t;          // destination slot id
    int r = flat >> 4, s = flat & 15;
    int g = s ^ (r & 15);
    const short* src = gbase + r * DIMK + g * 8;
    short* dst = lds + (i * 256 + w * 64) * 8;   // wave-uniform base; HW adds lane*16B
    __builtin_amdgcn_global_load_lds((gbl_void*)src, (lds_void*)dst, 16, 0, 0);
  }
}

// 64x64 wave tile, K=128, both operands in "row-major [idx][k]" swizzled LDS tiles.
// A frag: A[m=lane&15][k=quad*8+j]; B frag: B^T[n=lane&15][k=quad*8+j] (m89/m92-verified).
__device__ __forceinline__ void mfma_tile(const short* As, const short* Bs,
                                          f32x4 acc[4][4], int wrow, int wcol,
                                          int quad, int l15) {
#pragma unroll
  for (int ks = 0; ks < 4; ++ks) {
    int slot = (ks * 4 + quad) ^ l15;   // row&15 == l15 for all tiles
    bf16x8 a[4], b[4];
#pragma unroll
    for (int i = 0; i < 4; ++i) {
      a[i] = *(const bf16x8*)(As + (wrow + i * 16 + l15) * DIMK + slot * 8);
      b[i] = *(const bf16x8*)(Bs + (wcol + i * 16 + l15) * DIMK + slot * 8);
    }
#pragma unroll
    for (int i = 0; i < 4; ++i)
#pragma unroll
      for (int j = 0; j < 4; ++j)
        acc[i][j] = __builtin_amdgcn_mfma_f32_16x16x32_bf16(a[i], b[j], acc[i][j], 0, 0, 0);
  }
}

__device__ __forceinline__ int class_of(int col, const int* bnd_s) {
  int c = 0;
#pragma unroll
  for (int k = 1; k < DOUT; ++k) c += (col >= bnd_s[k]) ? 1 : 0;
  return c;
}

// ---------------- preprocessing: class-sort candidates ----------------
__global__ __launch_bounds__(256) void hist_kernel(const int* __restrict__ y,
                                                   int* __restrict__ cnt) {
  __shared__ int h[DOUT];
  int t = threadIdx.x;
  if (t < DOUT) h[t] = 0;
  __syncthreads();
  atomicAdd(&h[y[blockIdx.x * 256 + t]], 1);
  __syncthreads();
  if (t < DOUT) cnt[blockIdx.x * DOUT + t] = h[t];
}

__global__ __launch_bounds__(512) void scan_kernel(const int* __restrict__ cnt,
                                                   int* __restrict__ blockoff,
                                                   int* __restrict__ bnd) {
  __shared__ int buf[2][512 * DOUT];
  __shared__ int bndl[DOUT + 1];
  int t = threadIdx.x;
  int v[DOUT];
#pragma unroll
  for (int c = 0; c < DOUT; ++c) { v[c] = cnt[t * DOUT + c]; buf[0][t * DOUT + c] = v[c]; }
  __syncthreads();
  int src = 0;
  for (int off = 1; off < 512; off <<= 1) {
    int x[DOUT];
#pragma unroll
    for (int c = 0; c < DOUT; ++c) {
      x[c] = buf[src][t * DOUT + c];
      if (t >= off) x[c] += buf[src][(t - off) * DOUT + c];
    }
#pragma unroll
    for (int c = 0; c < DOUT; ++c) buf[1 - src][t * DOUT + c] = x[c];
    src ^= 1;
    __syncthreads();
  }
  if (t == 0) {
    bndl[0] = 0;
    for (int c = 0; c < DOUT; ++c) bndl[c + 1] = bndl[c] + buf[src][511 * DOUT + c];
    for (int k = 0; k <= DOUT; ++k) bnd[k] = bndl[k];
  }
  __syncthreads();
#pragma unroll
  for (int c = 0; c < DOUT; ++c)
    blockoff[t * DOUT + c] = bndl[c] + buf[src][t * DOUT + c] - v[c];  // exclusive
}

__global__ __launch_bounds__(256) void scatter_kernel(const int* __restrict__ y,
                                                      const int* __restrict__ blockoff,
                                                      int* __restrict__ invperm) {
  __shared__ int cur[DOUT];
  int t = threadIdx.x;
  if (t < DOUT) cur[t] = blockoff[blockIdx.x * DOUT + t];
  __syncthreads();
  int e = blockIdx.x * 256 + t;
  int p = atomicAdd(&cur[y[e]], 1);
  invperm[p] = e;   // sorted position -> original candidate index
}

// ---------------- encoder: rows @ W^T + b -> bf16 + sq norms ----------------
__global__ __launch_bounds__(256, 2) void encoder_kernel(
    const float* __restrict__ X, const float* __restrict__ W,
    const float* __restrict__ bias, const int* __restrict__ invperm,
    short* __restrict__ Zb, float* __restrict__ Sq) {
  __shared__ __align__(16) short As[DIMK * DIMK];   // X tile bf16 (swizzled)
  __shared__ __align__(16) short Bs[DIMK * DIMK];   // W bf16 (swizzled)
  __shared__ float bias_s[DIMK];
  __shared__ float sqacc[DIMK];
  int t = threadIdx.x;
  int rowbase = blockIdx.x * 128;
  if (t < DIMK) { bias_s[t] = bias[t]; sqacc[t] = 0.f; }
#pragma unroll
  for (int i = 0; i < 8; ++i) {
    int flat = i * 256 + t;
    int r = flat >> 4, sl = flat & 15;
    int g = sl ^ (r & 15);
    const float* srcW = W + r * DIMK + g * 8;
    float4 a0 = *(const float4*)srcW;
    float4 a1 = *(const float4*)(srcW + 4);
    s16x8 wv;
    wv[0] = f2bf(a0.x); wv[1] = f2bf(a0.y); wv[2] = f2bf(a0.z); wv[3] = f2bf(a0.w);
    wv[4] = f2bf(a1.x); wv[5] = f2bf(a1.y); wv[6] = f2bf(a1.z); wv[7] = f2bf(a1.w);
    *(s16x8*)(Bs + r * DIMK + sl * 8) = wv;
    int xr = rowbase + r;
    int gxr = invperm ? invperm[xr] : xr;
    const float* srcX = X + (size_t)gxr * DIMK + g * 8;
    float4 b0 = *(const float4*)srcX;
    float4 b1 = *(const float4*)(srcX + 4);
    s16x8 xv;
    xv[0] = f2bf(b0.x); xv[1] = f2bf(b0.y); xv[2] = f2bf(b0.z); xv[3] = f2bf(b0.w);
    xv[4] = f2bf(b1.x); xv[5] = f2bf(b1.y); xv[6] = f2bf(b1.z); xv[7] = f2bf(b1.w);
    *(s16x8*)(As + r * DIMK + sl * 8) = xv;
  }
  __syncthreads();
  int lane = t & 63, wid = t >> 6;
  int quad = lane >> 4, l15 = lane & 15;
  int wrow = (wid >> 1) * 64, wcol = (wid & 1) * 64;
  f32x4 acc[4][4];
  f32x4 z4 = {0.f, 0.f, 0.f, 0.f};
#pragma unroll
  for (int i = 0; i < 4; ++i)
#pragma unroll
    for (int j = 0; j < 4; ++j) acc[i][j] = z4;
  mfma_tile(As, Bs, acc, wrow, wcol, quad, l15);
#pragma unroll
  for (int ti = 0; ti < 4; ++ti) {
#pragma unroll
    for (int r = 0; r < 4; ++r) {
      int row_l = wrow + ti * 16 + quad * 4 + r;
      size_t grow = (size_t)(rowbase + row_l);
      float sqp = 0.f;
#pragma unroll
      for (int j = 0; j < 4; ++j) {
        int dcol = wcol + j * 16 + l15;
        float z = acc[ti][j][r] + bias_s[dcol];
        short hb = f2bf(z);
        float zr = bf2f(hb);           // sq computed from rounded value (consistency)
        sqp += zr * zr;
        Zb[grow * DIMK + dcol] = hb;
      }
      sqp += __shfl_xor(sqp, 1);
      sqp += __shfl_xor(sqp, 2);
      sqp += __shfl_xor(sqp, 4);
      sqp += __shfl_xor(sqp, 8);
      if (l15 == 0) atomicAdd(&sqacc[row_l], sqp);
    }
  }
  __syncthreads();
  if (t < DIMK) Sq[rowbase + t] = sqacc[t];
}

// ---------------- main fused GEMM + dist + exp + class-binned sums ----------------
__global__ __launch_bounds__(256, 2) void nca_main(
    const short* __restrict__ Zb, const short* __restrict__ Cb,
    const float* __restrict__ Sqz, const float* __restrict__ Sqc,
    const int* __restrict__ bnd, float* __restrict__ partials) {
  __shared__ __align__(16) short As[DIMK * DIMK];
  __shared__ __align__(16) short Bs[DIMK * DIMK];
  __shared__ float sqz_s[128];
  __shared__ float sqc_s[128];
  __shared__ int bnd_s[DOUT + 1];
  __shared__ float sacc[2][128][DOUT];   // per wave-column-half class sums

  int t = threadIdx.x;
  int lane = t & 63, wid = t >> 6;
  int quad = lane >> 4, l15 = lane & 15;
  int wrow = (wid >> 1) * 64, wcol = (wid & 1) * 64;
  int rowbase = blockIdx.y * 128;
  int colbase0 = blockIdx.x * (128 * CHUNK_ITERS);

  for (int i = t; i < 2 * 128 * DOUT; i += 256) (&sacc[0][0][0])[i] = 0.f;
  if (t < DOUT + 1) bnd_s[t] = bnd[t];
  if (t < 128) sqz_s[t] = Sqz[rowbase + t];
  stage_tile_async(Zb + (size_t)rowbase * DIMK, As, t);

  for (int it = 0; it < CHUNK_ITERS; ++it) {
    int colbase = colbase0 + it * 128;
    __syncthreads();                              // prev-iter LDS reads done
    stage_tile_async(Cb + (size_t)colbase * DIMK, Bs, t);
    if (t < 128) sqc_s[t] = Sqc[colbase + t];
    __syncthreads();                              // staging drained (vmcnt before barrier)

    f32x4 acc[4][4];
    f32x4 z4 = {0.f, 0.f, 0.f, 0.f};
#pragma unroll
    for (int i = 0; i < 4; ++i)
#pragma unroll
      for (int j = 0; j < 4; ++j) acc[i][j] = z4;
    mfma_tile(As, Bs, acc, wrow, wcol, quad, l15);

    int cfirst = class_of(colbase, bnd_s);
    int clast = class_of(colbase + 127, bnd_s);
    bool uni = (cfirst == clast);                 // wave-uniform; true except at 9 boundaries
    float sqcv[4]; int cls[4];
#pragma unroll
    for (int j = 0; j < 4; ++j) {
      int coll = wcol + j * 16 + l15;
      sqcv[j] = sqc_s[coll];
      cls[j] = class_of(colbase + coll, bnd_s);
    }
#pragma unroll
    for (int ti = 0; ti < 4; ++ti) {
#pragma unroll
      for (int r = 0; r < 4; ++r) {
        int row_l = wrow + ti * 16 + quad * 4 + r;
        float sz = sqz_s[row_l];
        float v[4];
#pragma unroll
        for (int j = 0; j < 4; ++j) {
          float sq = sz + sqcv[j] - 2.0f * acc[ti][j][r];
          float d = fast_sqrtf(fmaxf(sq, 1e-12f));
          v[j] = fast_exp2f(-LOG2E * d);          // e^{-dist}; no max-shift needed (d>=0)
        }
        if (uni) {
          float sum = (v[0] + v[1]) + (v[2] + v[3]);
          sum += __shfl_xor(sum, 1);
          sum += __shfl_xor(sum, 2);
          sum += __shfl_xor(sum, 4);
          sum += __shfl_xor(sum, 8);
          if (l15 == 0) sacc[wid & 1][row_l][cfirst] += sum;
        } else {
          for (int c = cfirst; c <= clast; ++c) {
            float sum = 0.f;
#pragma unroll
            for (int j = 0; j < 4; ++j) sum += (cls[j] == c) ? v[j] : 0.f;
            sum += __shfl_xor(sum, 1);
            sum += __shfl_xor(sum, 2);
            sum += __shfl_xor(sum, 4);
            sum += __shfl_xor(sum, 8);
            if (l15 == 0) sacc[wid & 1][row_l][c] += sum;
          }
        }
      }
    }
  }
  __syncthreads();
  if (t < 128) {
    size_t base = ((size_t)blockIdx.x * N_ROWS + rowbase + t) * DOUT;
#pragma unroll
    for (int c = 0; c < DOUT; ++c)
      partials[base + c] = sacc[0][t][c] + sacc[1][t][c];
  }
}

// ---------------- final reduce over chunks + log ----------------
__global__ __launch_bounds__(128) void reduce_kernel(const float* __restrict__ partials,
                                                     float* __restrict__ out) {
  __shared__ float s[128][DOUT];
  int row = blockIdx.x, t = threadIdx.x;
  const float* p = partials + ((size_t)t * N_ROWS + row) * DOUT;
#pragma unroll
  for (int c = 0; c < DOUT; ++c) s[t][c] = p[c];
  __syncthreads();
  for (int off = 64; off >= 1; off >>= 1) {
    if (t < off) {
#pragma unroll
      for (int c = 0; c < DOUT; ++c) s[t][c] += s[t + off][c];
    }
    __syncthreads();
  }
  if (t == 0) {
    float tot = 0.f;
#pragma unroll
    for (int c = 0; c < DOUT; ++c) tot += s[0][c];
    float inv = 1.0f / tot;
#pragma unroll
    for (int c = 0; c < DOUT; ++c)
      out[(size_t)row * DOUT + c] = logf(s[0][c] * inv + 1e-7f);
  }
}

extern "C" void kernel_launch(void* const* d_in, const int* in_sizes, int n_in,
                              void* d_out, int out_size, void* d_ws, size_t ws_size,
                              hipStream_t stream) {
  const float* x = (const float*)d_in[0];      // [2048][128]
  const float* cx = (const float*)d_in[1];     // [131072][128]
  const int* cy = (const int*)d_in[2];         // [131072]
  const float* W = (const float*)d_in[3];      // [128][128]
  const float* bias = (const float*)d_in[4];   // [128]
  float* out = (float*)d_out;
  char* ws = (char*)d_ws;

  size_t off = 0;
  auto alloc = [&](size_t bytes) {
    void* p = ws + off;
    off = (off + bytes + 255) & ~(size_t)255;
    return p;
  };
  short* Zb = (short*)alloc((size_t)N_ROWS * DIMK * 2);
  short* Cb = (short*)alloc((size_t)M_CAND * DIMK * 2);
  float* Sqz = (float*)alloc((size_t)N_ROWS * 4);
  float* Sqc = (float*)alloc((size_t)M_CAND * 4);
  int* invperm = (int*)alloc((size_t)M_CAND * 4);
  int* cnt = (int*)alloc(512 * DOUT * 4);
  int* blockoff = (int*)alloc(512 * DOUT * 4);
  int* bnd = (int*)alloc((DOUT + 1) * 4);
  float* partials = (float*)alloc((size_t)NCHUNK * N_ROWS * DOUT * 4);
  if (off > ws_size) return;   // ~45.7 MB needed

  hist_kernel<<<M_CAND / 256, 256, 0, stream>>>(cy, cnt);
  scan_kernel<<<1, 512, 0, stream>>>(cnt, blockoff, bnd);
  scatter_kernel<<<M_CAND / 256, 256, 0, stream>>>(cy, blockoff, invperm);
  encoder_kernel<<<N_ROWS / 128, 256, 0, stream>>>(x, W, bias, nullptr, Zb, Sqz);
  encoder_kernel<<<M_CAND / 128, 256, 0, stream>>>(cx, W, bias, invperm, Cb, Sqc);
  nca_main<<<dim3(NCHUNK, N_ROWS / 128), 256, 0, stream>>>(Zb, Cb, Sqz, Sqc, bnd, partials);
  reduce_kernel<<<N_ROWS, 128, 0, stream>>>(partials, out);
}

// Round 2
// 300.540 us; speedup vs baseline: 1.3846x; 1.3846x over previous
//
#include <hip/hip_runtime.h>
#include <stdint.h>
#include <math.h>

#define N_ROWS 2048
#define M_CAND 131072
#define DIMK 128
#define DOUT 10
#define COLS_PER_BLOCK 1024       // 8 tiles of 128 candidates
#define CHUNK_ITERS 8
#define CHUNKS_MAX 138            // ceil(M/1024) + DOUT  (class-padding worst case)
#define M_PAD_MAX (CHUNKS_MAX * COLS_PER_BLOCK)   // 141312
#define LOG2E 1.4426950408889634f
#define L2E2 (LOG2E * LOG2E)      // pre-scale so exp2(-sqrt(sq')) == exp(-sqrt(sq))

typedef __attribute__((ext_vector_type(8))) __bf16 bf16x8;   // MFMA A/B frag (4 VGPRs)
typedef __attribute__((ext_vector_type(8))) short s16x8;     // raw bf16 storage vec
typedef __attribute__((ext_vector_type(4))) float f32x4;     // MFMA C/D frag
typedef __attribute__((address_space(3))) void lds_void;
typedef const __attribute__((address_space(1))) void gbl_void;

__device__ __forceinline__ short f2bf(float f) {   // RNE fp32->bf16
  union { float f; unsigned u; } v; v.f = f;
  return (short)((v.u + 0x7fffu + ((v.u >> 16) & 1u)) >> 16);
}
__device__ __forceinline__ float bf2f(short h) {
  union { unsigned u; float f; } v;
  v.u = ((unsigned)(unsigned short)h) << 16; return v.f;
}
__device__ __forceinline__ float fast_sqrtf(float x) {
#if __has_builtin(__builtin_amdgcn_sqrtf)
  return __builtin_amdgcn_sqrtf(x);
#else
  return sqrtf(x);
#endif
}
__device__ __forceinline__ float fast_exp2f(float x) {
#if __has_builtin(__builtin_amdgcn_exp2f)
  return __builtin_amdgcn_exp2f(x);
#else
  return exp2f(x);
#endif
}

// Swizzled 128x128 bf16 tile: LDS slot (r,s) [16B granules] holds global granule g = s^(r&15).
// Staged direct-to-LDS; swizzle applied on the global source address (free).
__device__ __forceinline__ void stage_tile_async(const short* gbase, short* lds, int t) {
  int w = t >> 6;
#pragma unroll
  for (int i = 0; i < 8; ++i) {
    int flat = i * 256 + t;          // destination slot id
    int r = flat >> 4, s = flat & 15;
    int g = s ^ (r & 15);
    const short* src = gbase + r * DIMK + g * 8;
    short* dst = lds + (i * 256 + w * 64) * 8;   // wave-uniform base; HW adds lane*16B
    __builtin_amdgcn_global_load_lds((gbl_void*)src, (lds_void*)dst, 16, 0, 0);
  }
}

// 64x64 wave tile, K=128, both operands in "row-major [idx][k]" swizzled LDS tiles.
__device__ __forceinline__ void mfma_tile(const short* As, const short* Bs,
                                          f32x4 acc[4][4], int wrow, int wcol,
                                          int quad, int l15) {
#pragma unroll
  for (int ks = 0; ks < 4; ++ks) {
    int slot = (ks * 4 + quad) ^ l15;   // row&15 == l15 for all tiles
    bf16x8 a[4], b[4];
#pragma unroll
    for (int i = 0; i < 4; ++i) {
      a[i] = *(const bf16x8*)(As + (wrow + i * 16 + l15) * DIMK + slot * 8);
      b[i] = *(const bf16x8*)(Bs + (wcol + i * 16 + l15) * DIMK + slot * 8);
    }
#pragma unroll
    for (int i = 0; i < 4; ++i)
#pragma unroll
      for (int j = 0; j < 4; ++j)
        acc[i][j] = __builtin_amdgcn_mfma_f32_16x16x32_bf16(a[i], b[j], acc[i][j], 0, 0, 0);
  }
}

// ---------------- preprocessing: class-sort candidates (padded to 1024/class) ------------
__global__ __launch_bounds__(256) void fill_kernel(int* __restrict__ p, int v, int n) {
  int i = blockIdx.x * 256 + threadIdx.x;
  if (i < n) p[i] = v;
}

__global__ __launch_bounds__(256) void hist_kernel(const int* __restrict__ y,
                                                   int* __restrict__ cnt) {
  __shared__ int h[DOUT];
  int t = threadIdx.x;
  if (t < DOUT) h[t] = 0;
  __syncthreads();
  atomicAdd(&h[y[blockIdx.x * 256 + t]], 1);
  __syncthreads();
  if (t < DOUT) cnt[blockIdx.x * DOUT + t] = h[t];
}

__global__ __launch_bounds__(512) void scan_kernel(const int* __restrict__ cnt,
                                                   int* __restrict__ blockoff,
                                                   int* __restrict__ chunk_class) {
  __shared__ int buf[2][512 * DOUT];
  __shared__ int pbnd[DOUT + 1];
  int t = threadIdx.x;
  int v[DOUT];
#pragma unroll
  for (int c = 0; c < DOUT; ++c) { v[c] = cnt[t * DOUT + c]; buf[0][t * DOUT + c] = v[c]; }
  __syncthreads();
  int src = 0;
  for (int off = 1; off < 512; off <<= 1) {
    int x[DOUT];
#pragma unroll
    for (int c = 0; c < DOUT; ++c) {
      x[c] = buf[src][t * DOUT + c];
      if (t >= off) x[c] += buf[src][(t - off) * DOUT + c];
    }
#pragma unroll
    for (int c = 0; c < DOUT; ++c) buf[1 - src][t * DOUT + c] = x[c];
    src ^= 1;
    __syncthreads();
  }
  if (t == 0) {
    int pb = 0;
    pbnd[0] = 0;
    for (int c = 0; c < DOUT; ++c) {
      int tot = buf[src][511 * DOUT + c];
      pb += (tot + COLS_PER_BLOCK - 1) & ~(COLS_PER_BLOCK - 1);  // pad class to 1024
      pbnd[c + 1] = pb;
    }
    for (int i = 0; i < CHUNKS_MAX; ++i) {
      int col = i * COLS_PER_BLOCK, c = 0;
      for (int k = 1; k < DOUT; ++k) c += (col >= pbnd[k]) ? 1 : 0;
      chunk_class[i] = c;   // dead chunks get class 9; they contribute exactly 0
    }
  }
  __syncthreads();
#pragma unroll
  for (int c = 0; c < DOUT; ++c)
    blockoff[t * DOUT + c] = pbnd[c] + buf[src][t * DOUT + c] - v[c];  // padded exclusive
}

__global__ __launch_bounds__(256) void scatter_kernel(const int* __restrict__ y,
                                                      const int* __restrict__ blockoff,
                                                      int* __restrict__ invperm) {
  __shared__ int cur[DOUT];
  int t = threadIdx.x;
  if (t < DOUT) cur[t] = blockoff[blockIdx.x * DOUT + t];
  __syncthreads();
  int e = blockIdx.x * 256 + t;
  int p = atomicAdd(&cur[y[e]], 1);
  invperm[p] = e;   // padded sorted position -> original candidate index
}

// ---------------- encoder: rows @ W^T + b -> bf16 + sq norms ----------------
// invperm==nullptr: identity (x rows). invperm[row]<0: dead pad row -> Sq=1e30.
__global__ __launch_bounds__(256, 2) void encoder_kernel(
    const float* __restrict__ X, const float* __restrict__ W,
    const float* __restrict__ bias, const int* __restrict__ invperm,
    short* __restrict__ Zb, float* __restrict__ Sq) {
  __shared__ __align__(16) short As[DIMK * DIMK];   // X tile bf16 (swizzled)
  __shared__ __align__(16) short Bs[DIMK * DIMK];   // W bf16 (swizzled)
  __shared__ float bias_s[DIMK];
  __shared__ float sqacc[DIMK];
  int t = threadIdx.x;
  int rowbase = blockIdx.x * 128;
  if (t < DIMK) { bias_s[t] = bias[t]; sqacc[t] = 0.f; }
#pragma unroll
  for (int i = 0; i < 8; ++i) {
    int flat = i * 256 + t;
    int r = flat >> 4, sl = flat & 15;
    int g = sl ^ (r & 15);
    const float* srcW = W + r * DIMK + g * 8;
    float4 a0 = *(const float4*)srcW;
    float4 a1 = *(const float4*)(srcW + 4);
    s16x8 wv;
    wv[0] = f2bf(a0.x); wv[1] = f2bf(a0.y); wv[2] = f2bf(a0.z); wv[3] = f2bf(a0.w);
    wv[4] = f2bf(a1.x); wv[5] = f2bf(a1.y); wv[6] = f2bf(a1.z); wv[7] = f2bf(a1.w);
    *(s16x8*)(Bs + r * DIMK + sl * 8) = wv;
    int xr = rowbase + r;
    int gxr = invperm ? invperm[xr] : xr;
    const float* srcX = X + (size_t)(gxr < 0 ? 0 : gxr) * DIMK + g * 8;
    float4 b0 = *(const float4*)srcX;
    float4 b1 = *(const float4*)(srcX + 4);
    if (gxr < 0) { b0 = make_float4(0.f, 0.f, 0.f, 0.f); b1 = b0; }
    s16x8 xv;
    xv[0] = f2bf(b0.x); xv[1] = f2bf(b0.y); xv[2] = f2bf(b0.z); xv[3] = f2bf(b0.w);
    xv[4] = f2bf(b1.x); xv[5] = f2bf(b1.y); xv[6] = f2bf(b1.z); xv[7] = f2bf(b1.w);
    *(s16x8*)(As + r * DIMK + sl * 8) = xv;
  }
  __syncthreads();
  int lane = t & 63, wid = t >> 6;
  int quad = lane >> 4, l15 = lane & 15;
  int wrow = (wid >> 1) * 64, wcol = (wid & 1) * 64;
  f32x4 acc[4][4];
  f32x4 z4 = {0.f, 0.f, 0.f, 0.f};
#pragma unroll
  for (int i = 0; i < 4; ++i)
#pragma unroll
    for (int j = 0; j < 4; ++j) acc[i][j] = z4;
  mfma_tile(As, Bs, acc, wrow, wcol, quad, l15);
#pragma unroll
  for (int ti = 0; ti < 4; ++ti) {
#pragma unroll
    for (int r = 0; r < 4; ++r) {
      int row_l = wrow + ti * 16 + quad * 4 + r;
      size_t grow = (size_t)(rowbase + row_l);
      float sqp = 0.f;
#pragma unroll
      for (int j = 0; j < 4; ++j) {
        int dcol = wcol + j * 16 + l15;
        float z = acc[ti][j][r] + bias_s[dcol];
        short hb = f2bf(z);
        float zr = bf2f(hb);           // sq computed from rounded value (consistency)
        sqp += zr * zr;
        Zb[grow * DIMK + dcol] = hb;
      }
      sqp += __shfl_xor(sqp, 1);
      sqp += __shfl_xor(sqp, 2);
      sqp += __shfl_xor(sqp, 4);
      sqp += __shfl_xor(sqp, 8);
      if (l15 == 0) atomicAdd(&sqacc[row_l], sqp);
    }
  }
  __syncthreads();
  if (t < DIMK) {
    bool dead = invperm && (invperm[rowbase + t] < 0);
    Sq[rowbase + t] = dead ? 1e30f : sqacc[t];   // 1e30 -> exp2(-sqrt(~2e30)) == 0 exactly
  }
}

// ---------------- main fused GEMM + dist + exp + per-block (single-class) sum ----------
__global__ __launch_bounds__(256, 2) void nca_main(
    const short* __restrict__ Zb, const short* __restrict__ Cb,
    const float* __restrict__ Sqz, const float* __restrict__ Sqc,
    float* __restrict__ partials) {
  __shared__ __align__(16) short As[DIMK * DIMK];
  __shared__ __align__(16) short Bs[DIMK * DIMK];
  __shared__ float sqz_s[128];
  __shared__ float sqc_s[128];
  __shared__ float sacc[128];

  int t = threadIdx.x;
  int lane = t & 63, wid = t >> 6;
  int quad = lane >> 4, l15 = lane & 15;
  int wrow = (wid >> 1) * 64, wcol = (wid & 1) * 64;
  int rowbase = blockIdx.y * 128;
  int colbase0 = blockIdx.x * COLS_PER_BLOCK;

  if (t < 128) {
    sacc[t] = 0.f;
    sqz_s[t] = Sqz[rowbase + t] * L2E2;      // pre-scale: exp2(-sqrt(L2E^2 * sq))
  }
  stage_tile_async(Zb + (size_t)rowbase * DIMK, As, t);

  float sum[16];
#pragma unroll
  for (int i = 0; i < 16; ++i) sum[i] = 0.f;

  for (int it = 0; it < CHUNK_ITERS; ++it) {
    int colbase = colbase0 + it * 128;
    __syncthreads();                              // prev-iter LDS reads done
    stage_tile_async(Cb + (size_t)colbase * DIMK, Bs, t);
    if (t < 128) sqc_s[t] = Sqc[colbase + t] * L2E2;
    __syncthreads();                              // staging drained

    f32x4 acc[4][4];
    f32x4 z4 = {0.f, 0.f, 0.f, 0.f};
#pragma unroll
    for (int i = 0; i < 4; ++i)
#pragma unroll
      for (int j = 0; j < 4; ++j) acc[i][j] = z4;
    mfma_tile(As, Bs, acc, wrow, wcol, quad, l15);

    float sqcv[4];
#pragma unroll
    for (int j = 0; j < 4; ++j) sqcv[j] = sqc_s[wcol + j * 16 + l15];
#pragma unroll
    for (int ti = 0; ti < 4; ++ti) {
#pragma unroll
      for (int r = 0; r < 4; ++r) {
        int row_l = wrow + ti * 16 + quad * 4 + r;
        float sz = sqz_s[row_l];
        float v[4];
#pragma unroll
        for (int j = 0; j < 4; ++j) {
          float sq = fmaf(acc[ti][j][r], -2.0f * L2E2, sz + sqcv[j]);
          float d = fast_sqrtf(fmaxf(sq, 2.0e-12f));
          v[j] = fast_exp2f(-d);                  // == e^{-dist}; d>=0, no max-shift needed
        }
        sum[ti * 4 + r] += (v[0] + v[1]) + (v[2] + v[3]);
      }
    }
  }

  // once-per-block reduction: 16 lanes (l15) hold each row's column-partials
#pragma unroll
  for (int si = 0; si < 16; ++si) {
    float s = sum[si];
    s += __shfl_xor(s, 1);
    s += __shfl_xor(s, 2);
    s += __shfl_xor(s, 4);
    s += __shfl_xor(s, 8);
    if (l15 == 0) {
      int row_l = wrow + (si >> 2) * 16 + quad * 4 + (si & 3);
      atomicAdd(&sacc[row_l], s);                 // 2 column-half waves join here
    }
  }
  __syncthreads();
  if (t < 128)
    partials[(size_t)blockIdx.x * N_ROWS + rowbase + t] = sacc[t];
}

// ---------------- final reduce over chunks, class binning + log ----------------
__global__ __launch_bounds__(64) void reduce_kernel(const float* __restrict__ partials,
                                                    const int* __restrict__ chunk_class,
                                                    float* __restrict__ out) {
  int row = blockIdx.x, lane = threadIdx.x;
  float s = 0.f;
  for (int ch = 0; ch < CHUNKS_MAX; ++ch) {
    float p = partials[(size_t)ch * N_ROWS + row];
    int c = chunk_class[ch];
    s += (lane == c) ? p : 0.f;
  }
  float tot = s;
  tot += __shfl_xor(tot, 1);
  tot += __shfl_xor(tot, 2);
  tot += __shfl_xor(tot, 4);
  tot += __shfl_xor(tot, 8);
  tot += __shfl_xor(tot, 16);
  tot += __shfl_xor(tot, 32);
  if (lane < DOUT)
    out[(size_t)row * DOUT + lane] = logf(s / tot + 1e-7f);
}

extern "C" void kernel_launch(void* const* d_in, const int* in_sizes, int n_in,
                              void* d_out, int out_size, void* d_ws, size_t ws_size,
                              hipStream_t stream) {
  const float* x = (const float*)d_in[0];      // [2048][128]
  const float* cx = (const float*)d_in[1];     // [131072][128]
  const int* cy = (const int*)d_in[2];         // [131072]
  const float* W = (const float*)d_in[3];      // [128][128]
  const float* bias = (const float*)d_in[4];   // [128]
  float* out = (float*)d_out;
  char* ws = (char*)d_ws;

  size_t off = 0;
  auto alloc = [&](size_t bytes) {
    void* p = ws + off;
    off = (off + bytes + 255) & ~(size_t)255;
    return p;
  };
  short* Zb = (short*)alloc((size_t)N_ROWS * DIMK * 2);
  short* Cb = (short*)alloc((size_t)M_PAD_MAX * DIMK * 2);
  float* Sqz = (float*)alloc((size_t)N_ROWS * 4);
  float* Sqc = (float*)alloc((size_t)M_PAD_MAX * 4);
  int* invperm = (int*)alloc((size_t)M_PAD_MAX * 4);
  int* cnt = (int*)alloc(512 * DOUT * 4);
  int* blockoff = (int*)alloc(512 * DOUT * 4);
  int* chunk_class = (int*)alloc(CHUNKS_MAX * 4);
  float* partials = (float*)alloc((size_t)CHUNKS_MAX * N_ROWS * 4);
  if (off > ws_size) return;   // ~40 MB needed

  fill_kernel<<<(M_PAD_MAX + 255) / 256, 256, 0, stream>>>(invperm, -1, M_PAD_MAX);
  hist_kernel<<<M_CAND / 256, 256, 0, stream>>>(cy, cnt);
  scan_kernel<<<1, 512, 0, stream>>>(cnt, blockoff, chunk_class);
  scatter_kernel<<<M_CAND / 256, 256, 0, stream>>>(cy, blockoff, invperm);
  encoder_kernel<<<N_ROWS / 128, 256, 0, stream>>>(x, W, bias, nullptr, Zb, Sqz);
  encoder_kernel<<<M_PAD_MAX / 128, 256, 0, stream>>>(cx, W, bias, invperm, Cb, Sqc);
  nca_main<<<dim3(CHUNKS_MAX, N_ROWS / 128), 256, 0, stream>>>(Zb, Cb, Sqz, Sqc, partials);
  reduce_kernel<<<N_ROWS, 64, 0, stream>>>(partials, chunk_class, out);
}

// Round 3
// 262.872 us; speedup vs baseline: 1.5830x; 1.1433x over previous
//
#include <hip/hip_runtime.h>
#include <stdint.h>
#include <math.h>

#define N_ROWS 2048
#define M_CAND 131072
#define DIMK 128
#define DOUT 10
#define COLS_PER_BLOCK 1024       // one chunk per block (class-uniform, padded)
#define SUB_ITERS 16              // 16 sub-tiles of 64 candidates
#define CHUNKS_MAX 138            // ceil(M/1024) + DOUT (class-padding worst case)
#define M_PAD_MAX (CHUNKS_MAX * COLS_PER_BLOCK)   // 141312
#define LOG2E 1.4426950408889634f
#define L2E2 (LOG2E * LOG2E)      // pre-scale so exp2(-sqrt(sq')) == exp(-sqrt(sq))

typedef __attribute__((ext_vector_type(8))) __bf16 bf16x8;   // MFMA A/B frag (4 VGPRs)
typedef __attribute__((ext_vector_type(8))) short s16x8;     // raw bf16 storage vec
typedef __attribute__((ext_vector_type(4))) float f32x4;     // MFMA C/D frag
typedef __attribute__((address_space(3))) void lds_void;
typedef const __attribute__((address_space(1))) void gbl_void;

__device__ __forceinline__ short f2bf(float f) {   // RNE fp32->bf16
  union { float f; unsigned u; } v; v.f = f;
  return (short)((v.u + 0x7fffu + ((v.u >> 16) & 1u)) >> 16);
}
__device__ __forceinline__ float bf2f(short h) {
  union { unsigned u; float f; } v;
  v.u = ((unsigned)(unsigned short)h) << 16; return v.f;
}
__device__ __forceinline__ float fast_sqrtf(float x) {
#if __has_builtin(__builtin_amdgcn_sqrtf)
  return __builtin_amdgcn_sqrtf(x);
#else
  return sqrtf(x);
#endif
}
__device__ __forceinline__ float fast_exp2f(float x) {
#if __has_builtin(__builtin_amdgcn_exp2f)
  return __builtin_amdgcn_exp2f(x);
#else
  return exp2f(x);
#endif
}

// Swizzled 64x128 bf16 tile: LDS slot (r,s) [16B granules] holds global granule g = s^(r&15).
__device__ __forceinline__ void stage64(const short* gbase, short* lds, int t) {
  int w = t >> 6;
#pragma unroll
  for (int i = 0; i < 4; ++i) {
    int flat = i * 256 + t;
    int r = flat >> 4, s = flat & 15;
    int g = s ^ (r & 15);
    const short* src = gbase + r * DIMK + g * 8;
    short* dst = lds + (i * 256 + w * 64) * 8;   // wave-uniform base; HW adds lane*16B
    __builtin_amdgcn_global_load_lds((gbl_void*)src, (lds_void*)dst, 16, 0, 0);
  }
}

// Swizzled 128x128 tile stage (encoder only)
__device__ __forceinline__ void stage128(const short* gbase, short* lds, int t) {
  int w = t >> 6;
#pragma unroll
  for (int i = 0; i < 8; ++i) {
    int flat = i * 256 + t;
    int r = flat >> 4, s = flat & 15;
    int g = s ^ (r & 15);
    const short* src = gbase + r * DIMK + g * 8;
    short* dst = lds + (i * 256 + w * 64) * 8;
    __builtin_amdgcn_global_load_lds((gbl_void*)src, (lds_void*)dst, 16, 0, 0);
  }
}

// 64x64 wave tile, K=128 (encoder; both operands in swizzled 128x128 LDS tiles)
__device__ __forceinline__ void mfma_tile(const short* As, const short* Bs,
                                          f32x4 acc[4][4], int wrow, int wcol,
                                          int quad, int l15) {
#pragma unroll
  for (int ks = 0; ks < 4; ++ks) {
    int slot = (ks * 4 + quad) ^ l15;
    bf16x8 a[4], b[4];
#pragma unroll
    for (int i = 0; i < 4; ++i) {
      a[i] = *(const bf16x8*)(As + (wrow + i * 16 + l15) * DIMK + slot * 8);
      b[i] = *(const bf16x8*)(Bs + (wcol + i * 16 + l15) * DIMK + slot * 8);
    }
#pragma unroll
    for (int i = 0; i < 4; ++i)
#pragma unroll
      for (int j = 0; j < 4; ++j)
        acc[i][j] = __builtin_amdgcn_mfma_f32_16x16x32_bf16(a[i], b[j], acc[i][j], 0, 0, 0);
  }
}

// ---------------- preprocessing: class-sort candidates (padded to 1024/class) ------------
__global__ __launch_bounds__(256) void fill_kernel(int* __restrict__ p, int v, int n) {
  int i = blockIdx.x * 256 + threadIdx.x;
  if (i < n) p[i] = v;
}

__global__ __launch_bounds__(256) void hist_kernel(const int* __restrict__ y,
                                                   int* __restrict__ cnt) {
  __shared__ int h[DOUT];
  int t = threadIdx.x;
  if (t < DOUT) h[t] = 0;
  __syncthreads();
  atomicAdd(&h[y[blockIdx.x * 256 + t]], 1);
  __syncthreads();
  if (t < DOUT) cnt[blockIdx.x * DOUT + t] = h[t];
}

__global__ __launch_bounds__(512) void scan_kernel(const int* __restrict__ cnt,
                                                   int* __restrict__ blockoff,
                                                   int* __restrict__ chunk_class) {
  __shared__ int buf[2][512 * DOUT];
  __shared__ int pbnd[DOUT + 1];
  int t = threadIdx.x;
  int v[DOUT];
#pragma unroll
  for (int c = 0; c < DOUT; ++c) { v[c] = cnt[t * DOUT + c]; buf[0][t * DOUT + c] = v[c]; }
  __syncthreads();
  int src = 0;
  for (int off = 1; off < 512; off <<= 1) {
    int x[DOUT];
#pragma unroll
    for (int c = 0; c < DOUT; ++c) {
      x[c] = buf[src][t * DOUT + c];
      if (t >= off) x[c] += buf[src][(t - off) * DOUT + c];
    }
#pragma unroll
    for (int c = 0; c < DOUT; ++c) buf[1 - src][t * DOUT + c] = x[c];
    src ^= 1;
    __syncthreads();
  }
  if (t == 0) {
    int pb = 0;
    pbnd[0] = 0;
    for (int c = 0; c < DOUT; ++c) {
      int tot = buf[src][511 * DOUT + c];
      pb += (tot + COLS_PER_BLOCK - 1) & ~(COLS_PER_BLOCK - 1);  // pad class to 1024
      pbnd[c + 1] = pb;
    }
  }
  __syncthreads();
  if (t < CHUNKS_MAX) {             // parallel (was serial on t==0)
    int col = t * COLS_PER_BLOCK, c = 0;
#pragma unroll
    for (int k = 1; k < DOUT; ++k) c += (col >= pbnd[k]) ? 1 : 0;
    chunk_class[t] = c;             // dead chunks -> class 9; they contribute exactly 0
  }
#pragma unroll
  for (int c = 0; c < DOUT; ++c)
    blockoff[t * DOUT + c] = pbnd[c] + buf[src][t * DOUT + c] - v[c];  // padded exclusive
}

__global__ __launch_bounds__(256) void scatter_kernel(const int* __restrict__ y,
                                                      const int* __restrict__ blockoff,
                                                      int* __restrict__ invperm) {
  __shared__ int cur[DOUT];
  int t = threadIdx.x;
  if (t < DOUT) cur[t] = blockoff[blockIdx.x * DOUT + t];
  __syncthreads();
  int e = blockIdx.x * 256 + t;
  int p = atomicAdd(&cur[y[e]], 1);
  invperm[p] = e;   // padded sorted position -> original candidate index
}

// ---------------- encoder: rows @ W^T + b -> bf16 + sq norms ----------------
__global__ __launch_bounds__(256, 2) void encoder_kernel(
    const float* __restrict__ X, const float* __restrict__ W,
    const float* __restrict__ bias, const int* __restrict__ invperm,
    short* __restrict__ Zb, float* __restrict__ Sq) {
  __shared__ __align__(16) short As[DIMK * DIMK];
  __shared__ __align__(16) short Bs[DIMK * DIMK];
  __shared__ float bias_s[DIMK];
  __shared__ float sqacc[DIMK];
  int t = threadIdx.x;
  int rowbase = blockIdx.x * 128;
  if (t < DIMK) { bias_s[t] = bias[t]; sqacc[t] = 0.f; }
#pragma unroll
  for (int i = 0; i < 8; ++i) {
    int flat = i * 256 + t;
    int r = flat >> 4, sl = flat & 15;
    int g = sl ^ (r & 15);
    const float* srcW = W + r * DIMK + g * 8;
    float4 a0 = *(const float4*)srcW;
    float4 a1 = *(const float4*)(srcW + 4);
    s16x8 wv;
    wv[0] = f2bf(a0.x); wv[1] = f2bf(a0.y); wv[2] = f2bf(a0.z); wv[3] = f2bf(a0.w);
    wv[4] = f2bf(a1.x); wv[5] = f2bf(a1.y); wv[6] = f2bf(a1.z); wv[7] = f2bf(a1.w);
    *(s16x8*)(Bs + r * DIMK + sl * 8) = wv;
    int xr = rowbase + r;
    int gxr = invperm ? invperm[xr] : xr;
    const float* srcX = X + (size_t)(gxr < 0 ? 0 : gxr) * DIMK + g * 8;
    float4 b0 = *(const float4*)srcX;
    float4 b1 = *(const float4*)(srcX + 4);
    if (gxr < 0) { b0 = make_float4(0.f, 0.f, 0.f, 0.f); b1 = b0; }
    s16x8 xv;
    xv[0] = f2bf(b0.x); xv[1] = f2bf(b0.y); xv[2] = f2bf(b0.z); xv[3] = f2bf(b0.w);
    xv[4] = f2bf(b1.x); xv[5] = f2bf(b1.y); xv[6] = f2bf(b1.z); xv[7] = f2bf(b1.w);
    *(s16x8*)(As + r * DIMK + sl * 8) = xv;
  }
  __syncthreads();
  int lane = t & 63, wid = t >> 6;
  int quad = lane >> 4, l15 = lane & 15;
  int wrow = (wid >> 1) * 64, wcol = (wid & 1) * 64;
  f32x4 acc[4][4];
  f32x4 z4 = {0.f, 0.f, 0.f, 0.f};
#pragma unroll
  for (int i = 0; i < 4; ++i)
#pragma unroll
    for (int j = 0; j < 4; ++j) acc[i][j] = z4;
  mfma_tile(As, Bs, acc, wrow, wcol, quad, l15);
#pragma unroll
  for (int ti = 0; ti < 4; ++ti) {
#pragma unroll
    for (int r = 0; r < 4; ++r) {
      int row_l = wrow + ti * 16 + quad * 4 + r;
      size_t grow = (size_t)(rowbase + row_l);
      float sqp = 0.f;
#pragma unroll
      for (int j = 0; j < 4; ++j) {
        int dcol = wcol + j * 16 + l15;
        float z = acc[ti][j][r] + bias_s[dcol];
        short hb = f2bf(z);
        float zr = bf2f(hb);           // sq computed from rounded value (consistency)
        sqp += zr * zr;
        Zb[grow * DIMK + dcol] = hb;
      }
      sqp += __shfl_xor(sqp, 1);
      sqp += __shfl_xor(sqp, 2);
      sqp += __shfl_xor(sqp, 4);
      sqp += __shfl_xor(sqp, 8);
      if (l15 == 0) atomicAdd(&sqacc[row_l], sqp);
    }
  }
  __syncthreads();
  if (t < DIMK) {
    bool dead = invperm && (invperm[rowbase + t] < 0);
    Sq[rowbase + t] = dead ? 1e30f : sqacc[t];   // 1e30 -> exp(-sqrt) flushes to 0
  }
}

// ---------------- main fused GEMM + dist + exp + per-block sum ----------
// Grid: (x = rowblock [16], y = chunk [138]) -> consecutive blocks share the
// same Cb chunk (L2/L3 temporal locality). A-frags live in registers (loaded
// straight from global once); only B sub-tiles (64 cols, double-buffered) go
// through LDS. LDS ~37 KB + VGPR<=128 -> 4 blocks/CU (16 waves, 50% occ).
__global__ __launch_bounds__(256, 4) void nca_main(
    const short* __restrict__ Zb, const short* __restrict__ Cb,
    const float* __restrict__ Sqz, const float* __restrict__ Sqc,
    float* __restrict__ partials) {
  __shared__ __align__(16) short Bs[2][64 * DIMK];   // 2 x 16 KB
  __shared__ float sqc_s[COLS_PER_BLOCK];            // 4 KB

  int t = threadIdx.x;
  int lane = t & 63, wid = t >> 6;
  int quad = lane >> 4, l15 = lane & 15;
  int wrow = wid * 32;                 // each wave owns a private 32-row strip
  int rowbase = blockIdx.x * 128;
  int colbase0 = blockIdx.y * COLS_PER_BLOCK;

  stage64(Cb + (size_t)colbase0 * DIMK, &Bs[0][0], t);

#pragma unroll
  for (int i = 0; i < 4; ++i)
    sqc_s[i * 256 + t] = Sqc[colbase0 + i * 256 + t] * L2E2;

  // A fragments: A[m=l15][k=quad*8+j] per 16-row tile, direct from global.
  bf16x8 afrag[4][2];
#pragma unroll
  for (int ks = 0; ks < 4; ++ks)
#pragma unroll
    for (int ti = 0; ti < 2; ++ti)
      afrag[ks][ti] = *(const bf16x8*)(
          Zb + (size_t)(rowbase + wrow + ti * 16 + l15) * DIMK + ks * 32 + quad * 8);

  float szv[2][4];
#pragma unroll
  for (int ti = 0; ti < 2; ++ti)
#pragma unroll
    for (int r = 0; r < 4; ++r)
      szv[ti][r] = Sqz[rowbase + wrow + ti * 16 + quad * 4 + r] * L2E2;

  float sum[8];
#pragma unroll
  for (int i = 0; i < 8; ++i) sum[i] = 0.f;

  for (int it = 0; it < SUB_ITERS; ++it) {
    __syncthreads();     // drains stage of buf[it&1]; prev-iter reads complete
    if (it + 1 < SUB_ITERS)
      stage64(Cb + (size_t)(colbase0 + (it + 1) * 64) * DIMK, &Bs[(it + 1) & 1][0], t);
    const short* B = &Bs[it & 1][0];

    f32x4 acc[2][4];
    f32x4 z4 = {0.f, 0.f, 0.f, 0.f};
#pragma unroll
    for (int ti = 0; ti < 2; ++ti)
#pragma unroll
      for (int j = 0; j < 4; ++j) acc[ti][j] = z4;

#pragma unroll
    for (int ks = 0; ks < 4; ++ks) {
      int slot = (ks * 4 + quad) ^ l15;
      bf16x8 b[4];
#pragma unroll
      for (int j = 0; j < 4; ++j)
        b[j] = *(const bf16x8*)(B + (j * 16 + l15) * DIMK + slot * 8);
#pragma unroll
      for (int ti = 0; ti < 2; ++ti)
#pragma unroll
        for (int j = 0; j < 4; ++j)
          acc[ti][j] = __builtin_amdgcn_mfma_f32_16x16x32_bf16(afrag[ks][ti], b[j],
                                                               acc[ti][j], 0, 0, 0);
    }

    float sqcv[4];
#pragma unroll
    for (int j = 0; j < 4; ++j) sqcv[j] = sqc_s[it * 64 + j * 16 + l15];
#pragma unroll
    for (int ti = 0; ti < 2; ++ti)
#pragma unroll
      for (int r = 0; r < 4; ++r) {
        float base = szv[ti][r];
        float v[4];
#pragma unroll
        for (int j = 0; j < 4; ++j) {
          float sq = fmaf(acc[ti][j][r], -2.0f * L2E2, base + sqcv[j]);
          float d = fast_sqrtf(__builtin_fabsf(sq));   // abs folds into sqrt modifier
          v[j] = fast_exp2f(-d);                       // -d folds into exp modifier
        }
        sum[ti * 4 + r] += (v[0] + v[1]) + (v[2] + v[3]);
      }
  }

  // per-row column-sum: reduce across the 16 l15 lanes, once per block
#pragma unroll
  for (int si = 0; si < 8; ++si) {
    float s = sum[si];
    s += __shfl_xor(s, 1);
    s += __shfl_xor(s, 2);
    s += __shfl_xor(s, 4);
    s += __shfl_xor(s, 8);
    if (l15 == 0) {
      int row_l = wrow + (si >> 2) * 16 + quad * 4 + (si & 3);
      partials[(size_t)blockIdx.y * N_ROWS + rowbase + row_l] = s;
    }
  }
}

// ---------------- final reduce over chunks, class binning + log ----------------
__global__ __launch_bounds__(64) void reduce_kernel(const float* __restrict__ partials,
                                                    const int* __restrict__ chunk_class,
                                                    float* __restrict__ out) {
  int row = blockIdx.x, lane = threadIdx.x;
  float s = 0.f;
  for (int ch = 0; ch < CHUNKS_MAX; ++ch) {
    float p = partials[(size_t)ch * N_ROWS + row];
    int c = chunk_class[ch];
    s += (lane == c) ? p : 0.f;
  }
  float tot = s;
  tot += __shfl_xor(tot, 1);
  tot += __shfl_xor(tot, 2);
  tot += __shfl_xor(tot, 4);
  tot += __shfl_xor(tot, 8);
  tot += __shfl_xor(tot, 16);
  tot += __shfl_xor(tot, 32);
  if (lane < DOUT)
    out[(size_t)row * DOUT + lane] = logf(s / tot + 1e-7f);
}

extern "C" void kernel_launch(void* const* d_in, const int* in_sizes, int n_in,
                              void* d_out, int out_size, void* d_ws, size_t ws_size,
                              hipStream_t stream) {
  const float* x = (const float*)d_in[0];      // [2048][128]
  const float* cx = (const float*)d_in[1];     // [131072][128]
  const int* cy = (const int*)d_in[2];         // [131072]
  const float* W = (const float*)d_in[3];      // [128][128]
  const float* bias = (const float*)d_in[4];   // [128]
  float* out = (float*)d_out;
  char* ws = (char*)d_ws;

  size_t off = 0;
  auto alloc = [&](size_t bytes) {
    void* p = ws + off;
    off = (off + bytes + 255) & ~(size_t)255;
    return p;
  };
  short* Zb = (short*)alloc((size_t)N_ROWS * DIMK * 2);
  short* Cb = (short*)alloc((size_t)M_PAD_MAX * DIMK * 2);
  float* Sqz = (float*)alloc((size_t)N_ROWS * 4);
  float* Sqc = (float*)alloc((size_t)M_PAD_MAX * 4);
  int* invperm = (int*)alloc((size_t)M_PAD_MAX * 4);
  int* cnt = (int*)alloc(512 * DOUT * 4);
  int* blockoff = (int*)alloc(512 * DOUT * 4);
  int* chunk_class = (int*)alloc(CHUNKS_MAX * 4);
  float* partials = (float*)alloc((size_t)CHUNKS_MAX * N_ROWS * 4);
  if (off > ws_size) return;   // ~40 MB needed

  fill_kernel<<<(M_PAD_MAX + 255) / 256, 256, 0, stream>>>(invperm, -1, M_PAD_MAX);
  hist_kernel<<<M_CAND / 256, 256, 0, stream>>>(cy, cnt);
  scan_kernel<<<1, 512, 0, stream>>>(cnt, blockoff, chunk_class);
  scatter_kernel<<<M_CAND / 256, 256, 0, stream>>>(cy, blockoff, invperm);
  encoder_kernel<<<N_ROWS / 128, 256, 0, stream>>>(x, W, bias, nullptr, Zb, Sqz);
  encoder_kernel<<<M_PAD_MAX / 128, 256, 0, stream>>>(cx, W, bias, invperm, Cb, Sqc);
  nca_main<<<dim3(N_ROWS / 128, CHUNKS_MAX), 256, 0, stream>>>(Zb, Cb, Sqz, Sqc, partials);
  reduce_kernel<<<N_ROWS, 64, 0, stream>>>(partials, chunk_class, out);
}